// Round 5
// baseline (305.142 us; speedup 1.0000x reference)
//
#include <hip/hip_runtime.h>
#include <math.h>

#define BB 128
#define MM 35
#define PSZ 224
#define PP (PSZ*PSZ)          // 50176
#define SIGN_PENALTY 10.0f
#define RECON_WEIGHT 0.4f
#define DEFOCUS_RAD 1.0f
#define EPS_F 1e-8f
#define INV2PI 0.15915494309189535f

// CT factorization: 224 = 14*16.  n = 14*n2 + n1; k = 16*k1 + k2.
// Thread n1 owns slots {14n2+n1} == {k2*14+n1} → in-place LDS, bf16x2 packed.
// 16-pt DFT via radix-4^2 FFT (multiply-free DFT-4s + 9 twiddles);
// 14-pt via 2x7 DIT (two direct DFT-7 + 6 twiddles + 14 cadds).

// ws layout (floats):
//   [1] z_loss  [2..8] mask^2 partials (7)  [10] recon atomic sum  [11] counter
//   [2048 ..) phase [B][P][P]
//   [T_OFF ..) T [2][B][P][P] packed bf16x2
#define WS_PHASE_OFF    2048
#define WS_T_OFF        (WS_PHASE_OFF + BB*PP)
#define NBLK2           (14*BB*2)
#define S1 232            // stage1 LDS row stride (dwords)
#define S2 20             // stage2 LDS col-tile stride (dwords)

static constexpr float W16R[16] = {
    1.0f, 0.9238795325f, 0.7071067812f, 0.3826834324f, 0.0f,
    -0.3826834324f, -0.7071067812f, -0.9238795325f, -1.0f,
    -0.9238795325f, -0.7071067812f, -0.3826834324f, 0.0f,
    0.3826834324f, 0.7071067812f, 0.9238795325f};
static constexpr float W16I[16] = {
    0.0f, -0.3826834324f, -0.7071067812f, -0.9238795325f, -1.0f,
    -0.9238795325f, -0.7071067812f, -0.3826834324f, 0.0f,
    0.3826834324f, 0.7071067812f, 0.9238795325f, 1.0f,
    0.9238795325f, 0.7071067812f, 0.3826834324f};
static constexpr float W7R[7] = {
    1.0f, 0.6234898019f, -0.2225209340f, -0.9009688679f,
    -0.9009688679f, -0.2225209340f, 0.6234898019f};
static constexpr float W7I[7] = {
    0.0f, -0.7818314825f, -0.9749279122f, -0.4338837391f,
    0.4338837391f, 0.9749279122f, 0.7818314825f};
static constexpr float W14R[14] = {
    1.0f, 0.9009688679f, 0.6234898019f, 0.2225209340f, -0.2225209340f,
    -0.6234898019f, -0.9009688679f, -1.0f, -0.9009688679f,
    -0.6234898019f, -0.2225209340f, 0.2225209340f, 0.6234898019f,
    0.9009688679f};
static constexpr float W14I[14] = {
    0.0f, -0.4338837391f, -0.7818314825f, -0.9749279122f, -0.9749279122f,
    -0.7818314825f, -0.4338837391f, 0.0f, 0.4338837391f,
    0.7818314825f, 0.9749279122f, 0.9749279122f, 0.7818314825f,
    0.4338837391f};

__device__ __forceinline__ float lincoord(int i) {
    return -1.0f + 2.0f * (float)i / (float)(PSZ - 1);
}
__device__ __forceinline__ void fast_sincos(float x, float* s, float* c) {
    float rv = x * INV2PI;
    rv -= floorf(rv);
    *s = __builtin_amdgcn_sinf(rv);
    *c = __builtin_amdgcn_cosf(rv);
}
__device__ __forceinline__ void tw_sincos(int n1, float* s, float* c) {
    float rv = (float)n1 * (-1.0f / 224.0f);
    rv -= floorf(rv);
    *s = __builtin_amdgcn_sinf(rv);
    *c = __builtin_amdgcn_cosf(rv);
}
// round-half-up bf16x2 pack (4 inst)
__device__ __forceinline__ unsigned pack_bf2(float a, float b) {
    return ((__float_as_uint(a) + 0x8000u) >> 16) |
           ((__float_as_uint(b) + 0x8000u) & 0xffff0000u);
}
__device__ __forceinline__ float2 unpack_bf2(unsigned v) {
    return make_float2(__uint_as_float(v << 16), __uint_as_float(v & 0xffff0000u));
}
__device__ __forceinline__ float2 cmul(float2 a, float2 b) {
    return make_float2(fmaf(a.x, b.x, -a.y * b.y), fmaf(a.x, b.y, a.y * b.x));
}
// multiply-free forward DFT-4 (W4 = -i)
__device__ __forceinline__ void dft4(float2 a, float2 b, float2 c, float2 d,
                                     float2* o0, float2* o1, float2* o2, float2* o3) {
    float t0r = a.x + c.x, t0i = a.y + c.y;
    float t1r = b.x + d.x, t1i = b.y + d.y;
    float t2r = a.x - c.x, t2i = a.y - c.y;
    float t3r = b.x - d.x, t3i = b.y - d.y;
    *o0 = make_float2(t0r + t1r, t0i + t1i);
    *o2 = make_float2(t0r - t1r, t0i - t1i);
    *o1 = make_float2(t2r + t3i, t2i - t3r);
    *o3 = make_float2(t2r - t3i, t2i + t3r);
}
// 16-pt forward DFT, natural in/out order, radix-4 DIT (n = 4m+j)
__device__ __forceinline__ void fft16(const float2* x, float2* X) {
    float2 Y[4][4];
#pragma unroll
    for (int j = 0; j < 4; j++)
        dft4(x[j], x[4 + j], x[8 + j], x[12 + j],
             &Y[j][0], &Y[j][1], &Y[j][2], &Y[j][3]);
#pragma unroll
    for (int b = 0; b < 4; b++) {
        float2 z0 = Y[0][b];
        float2 z1 = cmul(Y[1][b], make_float2(W16R[(1 * b) & 15], W16I[(1 * b) & 15]));
        float2 z2 = cmul(Y[2][b], make_float2(W16R[(2 * b) & 15], W16I[(2 * b) & 15]));
        float2 z3 = cmul(Y[3][b], make_float2(W16R[(3 * b) & 15], W16I[(3 * b) & 15]));
        dft4(z0, z1, z2, z3, &X[b], &X[4 + b], &X[8 + b], &X[12 + b]);
    }
}
__device__ __forceinline__ void dft7(const float2* x, float2* X) {
#pragma unroll
    for (int k = 0; k < 7; k++) {
        float ar = x[0].x, ai = x[0].y;
#pragma unroll
        for (int n = 1; n < 7; n++) {
            const float wr = W7R[(n * k) % 7], wi = W7I[(n * k) % 7];
            ar = fmaf(x[n].x, wr, ar); ar = fmaf(-x[n].y, wi, ar);
            ai = fmaf(x[n].x, wi, ai); ai = fmaf(x[n].y, wr, ai);
        }
        X[k] = make_float2(ar, ai);
    }
}
// 14-pt forward DFT, natural order, 2x7 DIT (n = 2m+j)
__device__ __forceinline__ void dft14(const float2* x, float2* X) {
    float2 e[7], o[7], E[7], O[7];
#pragma unroll
    for (int r = 0; r < 7; r++) { e[r] = x[2 * r]; o[r] = x[2 * r + 1]; }
    dft7(e, E); dft7(o, O);
#pragma unroll
    for (int r = 0; r < 7; r++) {
        float2 op = cmul(O[r], make_float2(W14R[r], W14I[r]));
        X[r]     = make_float2(E[r].x + op.x, E[r].y + op.y);
        X[r + 7] = make_float2(E[r].x - op.x, E[r].y - op.y);
    }
}

// ---------------- k_phase: grid (197, 8). x<196: phase GEMM. x==196: small work.
__global__ __launch_bounds__(256) void k_phase(const float* __restrict__ pred,
                                               const float* __restrict__ target,
                                               const float* __restrict__ zern,
                                               const float* __restrict__ mask,
                                               float* __restrict__ phase,
                                               float* __restrict__ ws) {
    __shared__ float pl[16 * MM];
    __shared__ float red[256];
    int t = threadIdx.x;
    if (blockIdx.x == 196) {
        int y = blockIdx.y;
        float s = 0.f;
        if (y == 0) {
            if (t == 0) { ws[10] = 0.f; ((unsigned*)ws)[11] = 0u; }
            for (int i = t; i < BB * MM; i += 256) {
                float p = pred[i], tg = target[i];
                float dd = p - tg;
                float w = (p * tg < 0.f) ? SIGN_PENALTY : 1.f;
                s = fmaf(dd * dd, w, s);
            }
        } else {
            const float4* m4 = (const float4*)(mask + (y - 1) * (PP / 7));
            for (int i = t; i < PP / 28; i += 256) {   // 1792 float4
                float4 v = m4[i];
                s = fmaf(v.x, v.x, s); s = fmaf(v.y, v.y, s);
                s = fmaf(v.z, v.z, s); s = fmaf(v.w, v.w, s);
            }
        }
        red[t] = s;
        __syncthreads();
        for (int st = 128; st > 0; st >>= 1) {
            if (t < st) red[t] += red[t + st];
            __syncthreads();
        }
        if (t == 0) {
            if (y == 0) ws[1] = red[0] / (float)(BB * MM);
            else        ws[1 + y] = red[0];   // ws[2..8]
        }
        return;
    }
    int bg = blockIdx.y;
    for (int i = t; i < 16 * MM; i += 256) {
        int j = i / MM, m = i % MM;
        pl[i] = pred[(bg * 16 + j) * MM + m];
    }
    __syncthreads();
    int pix = blockIdx.x * 256 + t;
    float acc[16];
#pragma unroll
    for (int j = 0; j < 16; j++) acc[j] = 0.f;
    for (int m = 0; m < MM; m++) {
        float z = zern[m * PP + pix];
#pragma unroll
        for (int j = 0; j < 16; j++) acc[j] = fmaf(pl[j * MM + m], z, acc[j]);
    }
    float mk = mask[pix];
#pragma unroll
    for (int j = 0; j < 16; j++) phase[(size_t)(bg * 16 + j) * PP + pix] = acc[j] * mk;
}

// ---------------- stage 1: row DFTs, CT 14x16 (fft16 + dft14), bf16 ----------
__global__ __launch_bounds__(256, 6) void k_stage1(const float* __restrict__ phase,
                                                   const float* __restrict__ mask,
                                                   unsigned* __restrict__ T) {
    __shared__ unsigned xs[16 * S1];
    int h0 = blockIdx.x * 16;
    int b = blockIdx.y, d = blockIdx.z;
    int t = threadIdx.x;

    const float* ph_base = phase + (size_t)b * PP + (size_t)h0 * PSZ;
    for (int idx = t; idx < 16 * PSZ; idx += 256) {
        int r = idx / PSZ, w = idx - r * PSZ;
        float ph = ph_base[r * PSZ + w];
        if (d) {
            float vy = lincoord(h0 + r), vx = lincoord(w);
            ph += DEFOCUS_RAD * (2.f * (vx * vx + vy * vy) - 1.f);
        }
        float mk = mask[(h0 + r) * PSZ + w];
        float sn, cs;
        fast_sincos(ph, &sn, &cs);
        xs[r * S1 + w] = pack_bf2(mk * cs, mk * sn);
    }
    __syncthreads();

    if (t < 224) {                    // inner: 16 rows x 14 n1
        int r = t / 14, n1 = t - r * 14;
        unsigned* xr = xs + r * S1;
        float2 x[16], X[16];
#pragma unroll
        for (int n2 = 0; n2 < 16; n2++) x[n2] = unpack_bf2(xr[14 * n2 + n1]);
        fft16(x, X);
        float tw_s, tw_c;
        tw_sincos(n1, &tw_s, &tw_c);
        float2 step = make_float2(tw_c, tw_s), cur = make_float2(1.f, 0.f);
#pragma unroll
        for (int k2 = 0; k2 < 16; k2++) {
            float2 v = cmul(X[k2], cur);
            xr[k2 * 14 + n1] = pack_bf2(v.x, v.y);
            cur = cmul(cur, step);
        }
    }
    __syncthreads();

    {                                 // outer: 16 rows x 16 k2
        int r = t >> 4, k2 = t & 15;
        const unsigned* xr = xs + r * S1;
        float2 Bt[14], X[14];
#pragma unroll
        for (int n1 = 0; n1 < 14; n1++) Bt[n1] = unpack_bf2(xr[k2 * 14 + n1]);
        dft14(Bt, X);
        int img = d * BB + b;
        unsigned* Trow = T + ((size_t)img * PSZ + (h0 + r)) * PSZ;
#pragma unroll
        for (int k1 = 0; k1 < 14; k1++)
            Trow[16 * k1 + k2] = pack_bf2(X[k1].x, X[k1].y);
    }
}

// ---------------- stage 2: column DFTs + psf + loss + atomic finale ----------
__global__ __launch_bounds__(256, 6) void k_stage2(const unsigned* __restrict__ T,
                                                   const float* __restrict__ psfs,
                                                   float* __restrict__ ws,
                                                   float* __restrict__ out) {
    __shared__ unsigned xs[224 * S2];
    __shared__ float red[256];
    int tile = blockIdx.x, b = blockIdx.y, d = blockIdx.z;
    int img = d * BB + b;
    int col0 = tile * 16;
    int t = threadIdx.x;

    const unsigned* Tbase = T + (size_t)img * PP + col0;
    for (int idx = t; idx < 224 * 16; idx += 256) {
        int h = idx >> 4, c = idx & 15;
        xs[h * S2 + c] = Tbase[(size_t)h * PSZ + c];
    }
    __syncthreads();

    if (t < 224) {                    // inner: 14 n1 x 16 c
        int n1 = t >> 4, c = t & 15;
        float2 x[16], X[16];
#pragma unroll
        for (int n2 = 0; n2 < 16; n2++) x[n2] = unpack_bf2(xs[(14 * n2 + n1) * S2 + c]);
        fft16(x, X);
        float tw_s, tw_c;
        tw_sincos(n1, &tw_s, &tw_c);
        float2 step = make_float2(tw_c, tw_s), cur = make_float2(1.f, 0.f);
#pragma unroll
        for (int k2 = 0; k2 < 16; k2++) {
            float2 v = cmul(X[k2], cur);
            xs[(k2 * 14 + n1) * S2 + c] = pack_bf2(v.x, v.y);
            cur = cmul(cur, step);
        }
    }
    __syncthreads();

    float m2 = 0.f;
#pragma unroll
    for (int i = 0; i < 7; i++) m2 += ws[2 + i];       // uniform scalar loads
    float inv_denom = 1.f / (m2 * (float)PP + EPS_F);  // Parseval denominator

    int k2 = t >> 4, c = t & 15;
    float2 Bt[14];
#pragma unroll
    for (int n1 = 0; n1 < 14; n1++) Bt[n1] = unpack_bf2(xs[(k2 * 14 + n1) * S2 + c]);
    __syncthreads();   // all B-values in regs before psf writes clobber xs
    {
        float2 X[14];
        dft14(Bt, X);
#pragma unroll
        for (int k1 = 0; k1 < 14; k1++) {
            int kh = 16 * k1 + k2;
            xs[kh * S2 + c] =
                __float_as_uint(fmaf(X[k1].x, X[k1].x, X[k1].y * X[k1].y) * inv_denom);
        }
    }
    __syncthreads();

    int scol0 = 16 * ((tile + 7) % 14);
    const float* inp = psfs + ((size_t)b * 2 + d) * PP;
    float lsum = 0.f;
    for (int idx = t; idx < 224 * 16; idx += 256) {
        int kh = idx >> 4, cc = idx & 15;
        int skh = kh + 112; if (skh >= 224) skh -= 224;
        float diff = __uint_as_float(xs[kh * S2 + cc]) - inp[skh * PSZ + scol0 + cc];
        lsum = fmaf(diff, diff, lsum);
    }
    red[t] = lsum;
    __syncthreads();
    for (int st = 128; st > 0; st >>= 1) {
        if (t < st) red[t] += red[t + st];
        __syncthreads();
    }
    if (t == 0) {
        atomicAdd(&ws[10], red[0]);
        __threadfence();
        unsigned old = atomicAdd((unsigned*)ws + 11, 1u);
        if (old == NBLK2 - 1) {
            float total = atomicAdd(&ws[10], 0.f);
            float recon = total / (float)((size_t)BB * PP);
            out[0] = ws[1] + RECON_WEIGHT * recon;
        }
    }
}

extern "C" void kernel_launch(void* const* d_in, const int* in_sizes, int n_in,
                              void* d_out, int out_size, void* d_ws, size_t ws_size,
                              hipStream_t stream) {
    const float* pred   = (const float*)d_in[0];
    const float* target = (const float*)d_in[1];
    const float* psfs   = (const float*)d_in[2];
    const float* zern   = (const float*)d_in[3];
    const float* mask   = (const float*)d_in[4];

    float*    ws    = (float*)d_ws;
    float*    phase = ws + WS_PHASE_OFF;
    unsigned* T     = (unsigned*)(ws + WS_T_OFF);
    float*    out   = (float*)d_out;

    k_phase<<<dim3(197, 8), 256, 0, stream>>>(pred, target, zern, mask, phase, ws);
    k_stage1<<<dim3(14, BB, 2), 256, 0, stream>>>(phase, mask, T);
    k_stage2<<<dim3(14, BB, 2), 256, 0, stream>>>(T, psfs, ws, out);
}

// Round 6
// 302.781 us; speedup vs baseline: 1.0078x; 1.0078x over previous
//
#include <hip/hip_runtime.h>
#include <math.h>

#define BB 128
#define MM 35
#define PSZ 224
#define PP (PSZ*PSZ)          // 50176
#define SIGN_PENALTY 10.0f
#define RECON_WEIGHT 0.4f
#define DEFOCUS_RAD 1.0f
#define EPS_F 1e-8f
#define INV2PI 0.15915494309189535f

// CT factorization: 224 = 14*16.  n = 14*n2 + n1; k = 16*k1 + k2.
// Thread n1 owns slots {14n2+n1} == {k2*14+n1} → in-place LDS, bf16x2 packed.
// fft16: in-place radix-4^2, digit-reversed output slots (consumer permutes).
// dft14: sequential 2x7 DIT (load evens→DFT7→load odds→DFT7→combine) — lean liveness.

// ws layout (floats):
//   [1] z_loss  [2..8] mask^2 partials (7)  [10] recon atomic sum  [11] counter
//   [2048 ..) phase [B][P][P]
//   [T_OFF ..) T [2][B][P][P] packed bf16x2
#define WS_PHASE_OFF    2048
#define WS_T_OFF        (WS_PHASE_OFF + BB*PP)
#define NBLK2           (14*BB*2)
#define S1 232            // stage1 LDS row stride (dwords)
#define S2 20             // stage2 LDS col-tile stride (dwords)

static constexpr float W16R[16] = {
    1.0f, 0.9238795325f, 0.7071067812f, 0.3826834324f, 0.0f,
    -0.3826834324f, -0.7071067812f, -0.9238795325f, -1.0f,
    -0.9238795325f, -0.7071067812f, -0.3826834324f, 0.0f,
    0.3826834324f, 0.7071067812f, 0.9238795325f};
static constexpr float W16I[16] = {
    0.0f, -0.3826834324f, -0.7071067812f, -0.9238795325f, -1.0f,
    -0.9238795325f, -0.7071067812f, -0.3826834324f, 0.0f,
    0.3826834324f, 0.7071067812f, 0.9238795325f, 1.0f,
    0.9238795325f, 0.7071067812f, 0.3826834324f};
static constexpr float W7R[7] = {
    1.0f, 0.6234898019f, -0.2225209340f, -0.9009688679f,
    -0.9009688679f, -0.2225209340f, 0.6234898019f};
static constexpr float W7I[7] = {
    0.0f, -0.7818314825f, -0.9749279122f, -0.4338837391f,
    0.4338837391f, 0.9749279122f, 0.7818314825f};
static constexpr float W14R[7] = {
    1.0f, 0.9009688679f, 0.6234898019f, 0.2225209340f, -0.2225209340f,
    -0.6234898019f, -0.9009688679f};
static constexpr float W14I[7] = {
    0.0f, -0.4338837391f, -0.7818314825f, -0.9749279122f, -0.9749279122f,
    -0.7818314825f, -0.4338837391f};

__device__ __forceinline__ float lincoord(int i) {
    return -1.0f + 2.0f * (float)i / (float)(PSZ - 1);
}
__device__ __forceinline__ void fast_sincos(float x, float* s, float* c) {
    float rv = x * INV2PI;
    rv -= floorf(rv);
    *s = __builtin_amdgcn_sinf(rv);
    *c = __builtin_amdgcn_cosf(rv);
}
__device__ __forceinline__ void tw_sincos(int n1, float* s, float* c) {
    float rv = (float)n1 * (-1.0f / 224.0f);
    rv -= floorf(rv);
    *s = __builtin_amdgcn_sinf(rv);
    *c = __builtin_amdgcn_cosf(rv);
}
__device__ __forceinline__ unsigned pack_bf2(float a, float b) {
    return ((__float_as_uint(a) + 0x8000u) >> 16) |
           ((__float_as_uint(b) + 0x8000u) & 0xffff0000u);
}
__device__ __forceinline__ float2 unpack_bf2(unsigned v) {
    return make_float2(__uint_as_float(v << 16), __uint_as_float(v & 0xffff0000u));
}
__device__ __forceinline__ float2 cmul(float2 a, float2 b) {
    return make_float2(fmaf(a.x, b.x, -a.y * b.y), fmaf(a.x, b.y, a.y * b.x));
}
__device__ __forceinline__ float2 cmulc(float2 a, float wr, float wi) {
    return make_float2(fmaf(a.x, wr, -a.y * wi), fmaf(a.x, wi, a.y * wr));
}
__device__ __forceinline__ float2 cadd(float2 a, float2 b) {
    return make_float2(a.x + b.x, a.y + b.y);
}
__device__ __forceinline__ float2 csub(float2 a, float2 b) {
    return make_float2(a.x - b.x, a.y - b.y);
}
// multiply-free forward DFT-4
__device__ __forceinline__ void dft4(float2 a, float2 b, float2 c, float2 d,
                                     float2* o0, float2* o1, float2* o2, float2* o3) {
    float t0r = a.x + c.x, t0i = a.y + c.y;
    float t1r = b.x + d.x, t1i = b.y + d.y;
    float t2r = a.x - c.x, t2i = a.y - c.y;
    float t3r = b.x - d.x, t3i = b.y - d.y;
    *o0 = make_float2(t0r + t1r, t0i + t1i);
    *o2 = make_float2(t0r - t1r, t0i - t1i);
    *o1 = make_float2(t2r + t3i, t2i - t3r);
    *o3 = make_float2(t2r - t3i, t2i + t3r);
}
// In-place 16-pt forward DFT, radix-4 DIT.
// Input natural order in v[0..15]. Output: slot 4b+c holds X[4c+b]
// (digit-reversed); consumer uses FFT16_SLOT(k) = ((k&3)<<2)|(k>>2).
__device__ __forceinline__ void fft16_ip(float2* v) {
    // pass 1 (j = 0..3, hand-unrolled for trivial-twiddle folding):
    {   // j = 0: twiddles all 1
        float2 y0, y1, y2, y3;
        dft4(v[0], v[4], v[8], v[12], &y0, &y1, &y2, &y3);
        v[0] = y0; v[4] = y1; v[8] = y2; v[12] = y3;
    }
    {   // j = 1: W16^{1,2,3}
        float2 y0, y1, y2, y3;
        dft4(v[1], v[5], v[9], v[13], &y0, &y1, &y2, &y3);
        v[1] = y0;
        v[5]  = cmulc(y1, W16R[1], W16I[1]);
        v[9]  = cmulc(y2, W16R[2], W16I[2]);
        v[13] = cmulc(y3, W16R[3], W16I[3]);
    }
    {   // j = 2: W16^{2,4,6}; W16^4 = -i trivial
        float2 y0, y1, y2, y3;
        dft4(v[2], v[6], v[10], v[14], &y0, &y1, &y2, &y3);
        v[2] = y0;
        v[6]  = cmulc(y1, W16R[2], W16I[2]);
        v[10] = make_float2(y2.y, -y2.x);          // * (-i)
        v[14] = cmulc(y3, W16R[6], W16I[6]);
    }
    {   // j = 3: W16^{3,6,9}
        float2 y0, y1, y2, y3;
        dft4(v[3], v[7], v[11], v[15], &y0, &y1, &y2, &y3);
        v[3] = y0;
        v[7]  = cmulc(y1, W16R[3], W16I[3]);
        v[11] = cmulc(y2, W16R[6], W16I[6]);
        v[15] = cmulc(y3, W16R[9], W16I[9]);
    }
    // pass 2 (b = 0..3): DFT-4 over v[4b+0..3], write back same slots
#pragma unroll
    for (int b = 0; b < 4; b++) {
        float2 y0, y1, y2, y3;
        dft4(v[4 * b], v[4 * b + 1], v[4 * b + 2], v[4 * b + 3], &y0, &y1, &y2, &y3);
        v[4 * b] = y0; v[4 * b + 1] = y1; v[4 * b + 2] = y2; v[4 * b + 3] = y3;
    }
}
#define FFT16_SLOT(k) ((((k) & 3) << 2) | ((k) >> 2))

// direct 7-pt DFT; k=0 special-cased to adds
__device__ __forceinline__ void dft7(const float2* x, float2* X) {
    float sr = x[0].x, si = x[0].y;
#pragma unroll
    for (int n = 1; n < 7; n++) { sr += x[n].x; si += x[n].y; }
    X[0] = make_float2(sr, si);
#pragma unroll
    for (int k = 1; k < 7; k++) {
        float ar = x[0].x, ai = x[0].y;
#pragma unroll
        for (int n = 1; n < 7; n++) {
            const float wr = W7R[(n * k) % 7], wi = W7I[(n * k) % 7];
            ar = fmaf(x[n].x, wr, ar); ar = fmaf(-x[n].y, wi, ar);
            ai = fmaf(x[n].x, wi, ai); ai = fmaf(x[n].y, wr, ai);
        }
        X[k] = make_float2(ar, ai);
    }
}

// ---------------- k_phase: grid (197, 8). x<196: phase GEMM. x==196: small work.
__global__ __launch_bounds__(256) void k_phase(const float* __restrict__ pred,
                                               const float* __restrict__ target,
                                               const float* __restrict__ zern,
                                               const float* __restrict__ mask,
                                               float* __restrict__ phase,
                                               float* __restrict__ ws) {
    __shared__ float pl[16 * MM];
    __shared__ float red[256];
    int t = threadIdx.x;
    if (blockIdx.x == 196) {
        int y = blockIdx.y;
        float s = 0.f;
        if (y == 0) {
            if (t == 0) { ws[10] = 0.f; ((unsigned*)ws)[11] = 0u; }
            for (int i = t; i < BB * MM; i += 256) {
                float p = pred[i], tg = target[i];
                float dd = p - tg;
                float w = (p * tg < 0.f) ? SIGN_PENALTY : 1.f;
                s = fmaf(dd * dd, w, s);
            }
        } else {
            const float4* m4 = (const float4*)(mask + (y - 1) * (PP / 7));
            for (int i = t; i < PP / 28; i += 256) {
                float4 v = m4[i];
                s = fmaf(v.x, v.x, s); s = fmaf(v.y, v.y, s);
                s = fmaf(v.z, v.z, s); s = fmaf(v.w, v.w, s);
            }
        }
        red[t] = s;
        __syncthreads();
        for (int st = 128; st > 0; st >>= 1) {
            if (t < st) red[t] += red[t + st];
            __syncthreads();
        }
        if (t == 0) {
            if (y == 0) ws[1] = red[0] / (float)(BB * MM);
            else        ws[1 + y] = red[0];
        }
        return;
    }
    int bg = blockIdx.y;
    for (int i = t; i < 16 * MM; i += 256) {
        int j = i / MM, m = i % MM;
        pl[i] = pred[(bg * 16 + j) * MM + m];
    }
    __syncthreads();
    int pix = blockIdx.x * 256 + t;
    float acc[16];
#pragma unroll
    for (int j = 0; j < 16; j++) acc[j] = 0.f;
    for (int m = 0; m < MM; m++) {
        float z = zern[m * PP + pix];
#pragma unroll
        for (int j = 0; j < 16; j++) acc[j] = fmaf(pl[j * MM + m], z, acc[j]);
    }
    float mk = mask[pix];
#pragma unroll
    for (int j = 0; j < 16; j++) phase[(size_t)(bg * 16 + j) * PP + pix] = acc[j] * mk;
}

// ---------------- stage 1: row DFTs, CT 14x16 (fft16_ip + seq dft14) ---------
__global__ __launch_bounds__(256, 4) void k_stage1(const float* __restrict__ phase,
                                                   const float* __restrict__ mask,
                                                   unsigned* __restrict__ T) {
    __shared__ unsigned xs[16 * S1];
    int h0 = blockIdx.x * 16;
    int b = blockIdx.y, d = blockIdx.z;
    int t = threadIdx.x;

    const float* ph_base = phase + (size_t)b * PP + (size_t)h0 * PSZ;
    for (int idx = t; idx < 16 * PSZ; idx += 256) {
        int r = idx / PSZ, w = idx - r * PSZ;
        float ph = ph_base[r * PSZ + w];
        if (d) {
            float vy = lincoord(h0 + r), vx = lincoord(w);
            ph += DEFOCUS_RAD * (2.f * (vx * vx + vy * vy) - 1.f);
        }
        float mk = mask[(h0 + r) * PSZ + w];
        float sn, cs;
        fast_sincos(ph, &sn, &cs);
        xs[r * S1 + w] = pack_bf2(mk * cs, mk * sn);
    }
    __syncthreads();

    if (t < 224) {                    // inner: 16 rows x 14 n1
        int r = t / 14, n1 = t - r * 14;
        unsigned* xr = xs + r * S1;
        float2 v[16];
#pragma unroll
        for (int n2 = 0; n2 < 16; n2++) v[n2] = unpack_bf2(xr[14 * n2 + n1]);
        fft16_ip(v);
        float tw_s, tw_c;
        tw_sincos(n1, &tw_s, &tw_c);
        float2 step = make_float2(tw_c, tw_s), cur = make_float2(1.f, 0.f);
#pragma unroll
        for (int k2 = 0; k2 < 16; k2++) {
            float2 z = cmul(v[FFT16_SLOT(k2)], cur);
            xr[k2 * 14 + n1] = pack_bf2(z.x, z.y);
            cur = cmul(cur, step);
        }
    }
    __syncthreads();

    {                                 // outer: 16 rows x 16 k2, dft14 sequential
        int r = t >> 4, k2 = t & 15;
        const unsigned* xr = xs + r * S1;
        int img = d * BB + b;
        unsigned* Trow = T + ((size_t)img * PSZ + (h0 + r)) * PSZ;
        float2 e[7], E[7], O[7];
#pragma unroll
        for (int n = 0; n < 7; n++) e[n] = unpack_bf2(xr[k2 * 14 + 2 * n]);
        dft7(e, E);
#pragma unroll
        for (int n = 0; n < 7; n++) e[n] = unpack_bf2(xr[k2 * 14 + 2 * n + 1]);
        dft7(e, O);
        {   // r2 = 0: trivial twiddle
            Trow[k2]            = pack_bf2(E[0].x + O[0].x, E[0].y + O[0].y);
            Trow[16 * 7 + k2]   = pack_bf2(E[0].x - O[0].x, E[0].y - O[0].y);
        }
#pragma unroll
        for (int r2 = 1; r2 < 7; r2++) {
            float2 op = cmulc(O[r2], W14R[r2], W14I[r2]);
            float2 s = cadd(E[r2], op), q = csub(E[r2], op);
            Trow[16 * r2 + k2]       = pack_bf2(s.x, s.y);
            Trow[16 * (r2 + 7) + k2] = pack_bf2(q.x, q.y);
        }
    }
}

// ---------------- stage 2: column DFTs + psf + loss + atomic finale ----------
__global__ __launch_bounds__(256, 4) void k_stage2(const unsigned* __restrict__ T,
                                                   const float* __restrict__ psfs,
                                                   float* __restrict__ ws,
                                                   float* __restrict__ out) {
    __shared__ unsigned xs[224 * S2];
    __shared__ float red[256];
    int tile = blockIdx.x, b = blockIdx.y, d = blockIdx.z;
    int img = d * BB + b;
    int col0 = tile * 16;
    int t = threadIdx.x;

    const unsigned* Tbase = T + (size_t)img * PP + col0;
    for (int idx = t; idx < 224 * 16; idx += 256) {
        int h = idx >> 4, c = idx & 15;
        xs[h * S2 + c] = Tbase[(size_t)h * PSZ + c];
    }
    __syncthreads();

    if (t < 224) {                    // inner: 14 n1 x 16 c
        int n1 = t >> 4, c = t & 15;
        float2 v[16];
#pragma unroll
        for (int n2 = 0; n2 < 16; n2++) v[n2] = unpack_bf2(xs[(14 * n2 + n1) * S2 + c]);
        fft16_ip(v);
        float tw_s, tw_c;
        tw_sincos(n1, &tw_s, &tw_c);
        float2 step = make_float2(tw_c, tw_s), cur = make_float2(1.f, 0.f);
#pragma unroll
        for (int k2 = 0; k2 < 16; k2++) {
            float2 z = cmul(v[FFT16_SLOT(k2)], cur);
            xs[(k2 * 14 + n1) * S2 + c] = pack_bf2(z.x, z.y);
            cur = cmul(cur, step);
        }
    }
    __syncthreads();

    float m2 = 0.f;
#pragma unroll
    for (int i = 0; i < 7; i++) m2 += ws[2 + i];       // uniform scalar loads
    float inv_denom = 1.f / (m2 * (float)PP + EPS_F);  // Parseval denominator

    int k2 = t >> 4, c = t & 15;
    float2 e[7], E[7], O[7];
#pragma unroll
    for (int n = 0; n < 7; n++) e[n] = unpack_bf2(xs[(k2 * 14 + 2 * n) * S2 + c]);
    dft7(e, E);
#pragma unroll
    for (int n = 0; n < 7; n++) e[n] = unpack_bf2(xs[(k2 * 14 + 2 * n + 1) * S2 + c]);
    dft7(e, O);
    __syncthreads();   // all reads done before psf writes clobber xs
    {
        float2 s0 = cadd(E[0], O[0]), q0 = csub(E[0], O[0]);
        xs[k2 * S2 + c] = __float_as_uint(fmaf(s0.x, s0.x, s0.y * s0.y) * inv_denom);
        xs[(16 * 7 + k2) * S2 + c] =
            __float_as_uint(fmaf(q0.x, q0.x, q0.y * q0.y) * inv_denom);
    }
#pragma unroll
    for (int r2 = 1; r2 < 7; r2++) {
        float2 op = cmulc(O[r2], W14R[r2], W14I[r2]);
        float2 s = cadd(E[r2], op), q = csub(E[r2], op);
        xs[(16 * r2 + k2) * S2 + c] =
            __float_as_uint(fmaf(s.x, s.x, s.y * s.y) * inv_denom);
        xs[(16 * (r2 + 7) + k2) * S2 + c] =
            __float_as_uint(fmaf(q.x, q.x, q.y * q.y) * inv_denom);
    }
    __syncthreads();

    int scol0 = 16 * ((tile + 7) % 14);
    const float* inp = psfs + ((size_t)b * 2 + d) * PP;
    float lsum = 0.f;
    for (int idx = t; idx < 224 * 16; idx += 256) {
        int kh = idx >> 4, cc = idx & 15;
        int skh = kh + 112; if (skh >= 224) skh -= 224;
        float diff = __uint_as_float(xs[kh * S2 + cc]) - inp[skh * PSZ + scol0 + cc];
        lsum = fmaf(diff, diff, lsum);
    }
    red[t] = lsum;
    __syncthreads();
    for (int st = 128; st > 0; st >>= 1) {
        if (t < st) red[t] += red[t + st];
        __syncthreads();
    }
    if (t == 0) {
        atomicAdd(&ws[10], red[0]);
        __threadfence();
        unsigned old = atomicAdd((unsigned*)ws + 11, 1u);
        if (old == NBLK2 - 1) {
            float total = atomicAdd(&ws[10], 0.f);
            float recon = total / (float)((size_t)BB * PP);
            out[0] = ws[1] + RECON_WEIGHT * recon;
        }
    }
}

extern "C" void kernel_launch(void* const* d_in, const int* in_sizes, int n_in,
                              void* d_out, int out_size, void* d_ws, size_t ws_size,
                              hipStream_t stream) {
    const float* pred   = (const float*)d_in[0];
    const float* target = (const float*)d_in[1];
    const float* psfs   = (const float*)d_in[2];
    const float* zern   = (const float*)d_in[3];
    const float* mask   = (const float*)d_in[4];

    float*    ws    = (float*)d_ws;
    float*    phase = ws + WS_PHASE_OFF;
    unsigned* T     = (unsigned*)(ws + WS_T_OFF);
    float*    out   = (float*)d_out;

    k_phase<<<dim3(197, 8), 256, 0, stream>>>(pred, target, zern, mask, phase, ws);
    k_stage1<<<dim3(14, BB, 2), 256, 0, stream>>>(phase, mask, T);
    k_stage2<<<dim3(14, BB, 2), 256, 0, stream>>>(T, psfs, ws, out);
}